// Round 8
// baseline (1009.065 us; speedup 1.0000x reference)
//
#include <hip/hip_runtime.h>
#include <stdint.h>

// ---------------- types ----------------
typedef unsigned short ush;
typedef __bf16   bf16x8 __attribute__((ext_vector_type(8)));
typedef float    f32x4  __attribute__((ext_vector_type(4)));
typedef uint32_t u32x4  __attribute__((ext_vector_type(4)));

union U16B { u32x4 u; bf16x8 b; };
union P8   { ush us[8]; u32x4 v; };

template<int V> struct ICx { static constexpr int value = V; };

__device__ __forceinline__ ush f2bf(float f) {
    union { float f; uint32_t u; } v; v.f = f;
    uint32_t r = v.u + 0x7FFFu + ((v.u >> 16) & 1u);   // RNE
    return (ush)(r >> 16);
}

__device__ __forceinline__ void gl_lds16(const ush* g, ush* l) {
    __builtin_amdgcn_global_load_lds(
        (const __attribute__((address_space(1))) uint32_t*)g,
        (__attribute__((address_space(3))) uint32_t*)l, 16, 0, 0);
}

// problem constants
#define HWPX  3136
// ws layout (bytes)
#define POOL_OFF   58720256UL   // 8192 f32
#define ATT_OFF    58753024UL   // 16384 f32
#define WAGG_OFF   58818560UL   // 32*9*256*256 bf16

// ---------------- kernel 0: zero xT halo cols {0,57} + pooled ----------------
__global__ void k_halo(u32x4* __restrict__ xT16, u32x4* __restrict__ pooled16) {
    int i = blockIdx.x * 256 + threadIdx.x;        // 448 blocks -> 114688
    int rl = i >> 3, s = i & 7;
    u32x4 z = (u32x4)(0u);
    size_t byte = (size_t)rl * 4096 + (s < 4 ? s * 16 : 3648 + (s - 4) * 16);
    xT16[byte >> 4] = z;
    if (blockIdx.x < 8) pooled16[blockIdx.x * 256 + threadIdx.x] = z;  // full 32KB
}

// ---------------- kernel 1: transpose x -> xT bf16 (swizzled) + pooled sums --
// xT layout: [b][icg32 0..7][row 0..55][padcol 0..63][ic 0..31]
//   padcol p: p=0 and p=57 are zero halo; p=1..56 <-> image col p-1; 58..63 dead
//   sub 's' stored at slot s ^ ((p>>1)&3): injective on every 8-col window
__global__ void k_transpose(const float* __restrict__ x, ush* __restrict__ xT,
                            float* __restrict__ pooled) {
    __shared__ float tile[64][65];
    int blk = blockIdx.x;                 // 32 * 4 * 49
    int b   = blk / 196;
    int rem = blk % 196;
    int icg = rem / 49;                   // 64-ic group
    int pxg = rem % 49;                   // 64-px group
    int t = threadIdx.x;

    {
        int icl  = t >> 2, part = t & 3;
        const float* src = x + (size_t)(b * 256 + icg * 64 + icl) * HWPX + pxg * 64 + part * 16;
        #pragma unroll
        for (int k = 0; k < 4; ++k) {
            f32x4 v = *(const f32x4*)(src + k * 4);
            tile[icl][part * 16 + k * 4 + 0] = v[0];
            tile[icl][part * 16 + k * 4 + 1] = v[1];
            tile[icl][part * 16 + k * 4 + 2] = v[2];
            tile[icl][part * 16 + k * 4 + 3] = v[3];
        }
    }
    __syncthreads();

    if (t < 64) {
        float s = 0.f;
        #pragma unroll 8
        for (int p = 0; p < 64; ++p) s += tile[t][p];
        atomicAdd(pooled + b * 256 + icg * 64 + t, s);
    }

    {
        int pxl = t >> 2, icq = t & 3;
        int px  = pxg * 64 + pxl;
        int row = px / 56;
        int col = px - row * 56;
        int p   = col + 1;
        int xorp = (p >> 1) & 3;
        int icg32   = icg * 2 + (icq >> 1);
        int subbase = (icq & 1) * 2;
        P8 lo, hi;
        #pragma unroll
        for (int m = 0; m < 8; ++m) {
            lo.us[m] = f2bf(tile[icq * 16 + m][pxl]);
            hi.us[m] = f2bf(tile[icq * 16 + 8 + m][pxl]);
        }
        size_t base = (((size_t)(b * 8 + icg32) * 56 + row) * 64 + p) * 32;
        *(u32x4*)(xT + base + (size_t)((subbase ^ xorp) * 8))       = lo.v;
        *(u32x4*)(xT + base + (size_t)(((subbase + 1) ^ xorp) * 8)) = hi.v;
    }
}

// ---------------- kernel 2: attention (1 block, 512 threads) ----------------
__global__ void k_attn(const float* __restrict__ pooled,
                       const float* __restrict__ fc1_w, const float* __restrict__ fc1_b,
                       const float* __restrict__ ln_g,  const float* __restrict__ ln_b,
                       const float* __restrict__ sp_w,  const float* __restrict__ sp_b,
                       float* __restrict__ att) {
    __shared__ float hs[32][16];
    int t = threadIdx.x;
    {
        int b = t >> 4, j = t & 15;
        float acc = 0.f;
        for (int c = 0; c < 256; ++c) acc += pooled[b * 256 + c] * fc1_w[j * 256 + c];
        hs[b][j] = fc1_b[j] + acc * (1.0f / 3136.0f);
    }
    __syncthreads();
    if (t < 32) {
        float mu = 0.f;
        #pragma unroll
        for (int j = 0; j < 16; ++j) mu += hs[t][j];
        mu *= (1.0f / 16.0f);
        float var = 0.f;
        #pragma unroll
        for (int j = 0; j < 16; ++j) { float d = hs[t][j] - mu; var += d * d; }
        var *= (1.0f / 16.0f);
        float inv = rsqrtf(var + 1e-5f);
        #pragma unroll
        for (int j = 0; j < 16; ++j) {
            float v = (hs[t][j] - mu) * inv * ln_g[j] + ln_b[j];
            hs[t][j] = fmaxf(v, 0.f);
        }
    }
    __syncthreads();
    {
        int b = t >> 4, m = t & 15;
        float a[33];
        #pragma unroll 1
        for (int i = 0; i < 33; ++i) {
            int p = m * 33 + i;
            float acc = sp_b[p];
            #pragma unroll
            for (int j = 0; j < 16; ++j) acc += hs[b][j] * sp_w[p * 16 + j];
            a[i] = acc;
        }
        float s = 0.f;
        #pragma unroll
        for (int i = 0; i < 33; ++i) s += fabsf(a[i]);
        float inv = 1.0f / (s + 0.001f);
        #pragma unroll
        for (int c = 0; c < 32; ++c) att[(b * 16 + m) * 32 + c] = a[c] * inv;
    }
}

// ---------------- kernel 3: aggregate weights -> Wagg bf16 [b][tap][oc][ic] --
__global__ void k_agg(const float* __restrict__ cells, const float* __restrict__ att,
                      ush* __restrict__ wagg) {
    __shared__ float at[512];
    int blk = blockIdx.x;                 // 32*64
    int b = blk >> 6, co = blk & 63;
    int t = threadIdx.x;
    for (int i = t; i < 512; i += 256) at[i] = att[b * 512 + i];
    __syncthreads();
    int ci = t & 63, gi = t >> 6;
    float acc[4][9];
    #pragma unroll
    for (int g = 0; g < 4; ++g)
        #pragma unroll
        for (int k = 0; k < 9; ++k) acc[g][k] = 0.f;
    for (int c = 0; c < 32; ++c) {
        float a0 = at[(0 + gi) * 32 + c];
        float a1 = at[(4 + gi) * 32 + c];
        float a2 = at[(8 + gi) * 32 + c];
        float a3 = at[(12 + gi) * 32 + c];
        const float* cp = cells + (size_t)c * 36864 + co * 576 + ci * 9;
        #pragma unroll
        for (int k = 0; k < 9; ++k) {
            float cv = cp[k];
            acc[0][k] += a0 * cv; acc[1][k] += a1 * cv;
            acc[2][k] += a2 * cv; acc[3][k] += a3 * cv;
        }
    }
    #pragma unroll
    for (int g = 0; g < 4; ++g)
        #pragma unroll
        for (int k = 0; k < 9; ++k)
            wagg[((size_t)(b * 9 + k) * 256 + g * 64 + co) * 256 + gi * 64 + ci] = f2bf(acc[g][k]);
}

// ---------------- kernel 4: conv via implicit-GEMM MFMA ----------------
// A = x pixels (M), B = weights (N=oc); wave = 112 px x 64 oc (7 x-frags x 4 w-frags)
// block: (b, 128-oc tile, 4-row tile); 4 waves = 2 px-halves x 2 oc-halves
// ANTI-LOCKSTEP: each block starts its (commutative) K-chunk loop at a
// different chunk (c0 = kk % 7) so co-resident blocks de-phase and their
// LDS/L2/MFMA bursts interleave instead of serializing. 3 blocks/CU.
__global__ __launch_bounds__(256, 3) void k_conv(const ush* __restrict__ xT,
                                                 const ush* __restrict__ wagg,
                                                 float* __restrict__ out) {
    __shared__ __align__(16) ush xs[2][12288];   // [buf][row6][col64][ic32]

    int tid = threadIdx.x;
    // XCD-grouped: 14 spatial tiles of one (b,octile) land on one XCD
    int wg  = blockIdx.x;                // 896
    int xcd = wg & 7;
    int kk  = wg >> 3;                   // 0..111
    int gq  = kk / 14;                   // 0..7
    int sp  = kk - gq * 14;              // spatial tile 0..13
    int g   = gq * 8 + xcd;              // 0..63
    int b   = g >> 1, octile = g & 1;
    int row0 = sp * 4, oc0 = octile * 128;
    int c0  = kk % 7;                    // chunk-rotation stagger (kk,kk+32,kk+64 differ)

    int lane = tid & 63, w = tid >> 6;
    int wm = w >> 1, wn = w & 1;         // wm: oc half (64), wn: px half (112)
    int l15 = lane & 15, s4 = lane >> 4;

    {   // zero both LDS buffers (invalid rows stay zero forever)
        u32x4 z = (u32x4)(0u);
        #pragma unroll
        for (int i = 0; i < 12; ++i) ((u32x4*)xs)[tid + i * 256] = z;
    }

    int prow[7], pq[7];
    #pragma unroll
    for (int j = 0; j < 7; ++j) {
        int px = wn * 112 + j * 16 + l15;
        prow[j] = px / 56;
        pq[j]   = px - prow[j] * 56;
    }

    unsigned vmask = 0;
    #pragma unroll
    for (int k = 0; k < 6; ++k) {
        int grow = row0 - 1 + k;
        if (grow >= 0 && grow < 56) vmask |= 1u << k;
    }

    // weight base: frag mi -> oc = oc0 + wm*64 + mi*16 + l15, ic = s4*8..+8
    const ush* wb = wagg + (size_t)b * 9 * 65536 + (size_t)(oc0 + wm * 64 + l15) * 256 + s4 * 8;
    const ush* xb = xT + (size_t)b * 8 * 56 * 2048 + (size_t)tid * 8;   // per-lane
    ush* lq = &xs[0][0];

    f32x4 acc[4][7];
    #pragma unroll
    for (int mi = 0; mi < 4; ++mi)
        #pragma unroll
        for (int j = 0; j < 7; ++j) acc[mi][j] = (f32x4)(0.f);

    __syncthreads();                      // LDS zero visible before DMA

    // prologue: DMA x chunk c0 -> buf 0
    #pragma unroll
    for (int k = 0; k < 6; ++k)
        if (vmask & (1u << k))
            gl_lds16(xb + (size_t)(c0 * 56 + row0 - 1 + k) * 2048, lq + k * 2048 + w * 512);
    __syncthreads();

    auto chunk_body = [&](auto parc, int i) {
        constexpr int PAR = decltype(parc)::value;    // == i & 1 (LDS buffer)
        int cc = c0 + i; if (cc >= 8) cc -= 8;        // rotated chunk index
        const ush* wc = wb + (size_t)cc * 32;
        const ush* xsb = xs[PAR];

        if (i < 7) {   // DMA next rotated chunk into the other buffer
            int cn = cc + 1; if (cn >= 8) cn -= 8;
            #pragma unroll
            for (int k = 0; k < 6; ++k)
                if (vmask & (1u << k))
                    gl_lds16(xb + (size_t)(cn * 56 + row0 - 1 + k) * 2048,
                             lq + (PAR ^ 1) * 12288 + k * 2048 + w * 512);
        }

        // weight batches for this chunk (taps 0..3), reloads feed 4..8
        U16B wA[2][4], wB[2][4];
        #pragma unroll
        for (int t = 0; t < 2; ++t)
            #pragma unroll
            for (int mi = 0; mi < 4; ++mi) {
                wA[t][mi].u = *(const u32x4*)(wc + (size_t)t * 65536 + mi * 4096);
                wB[t][mi].u = *(const u32x4*)(wc + (size_t)(t + 2) * 65536 + mi * 4096);
            }

        auto do_tap = [&](int dy, int dx, U16B (&wf)[4]) {
            U16B bx[7];
            #pragma unroll
            for (int j = 0; j < 7; ++j) {
                int q    = pq[j] + dx;
                int slot = s4 ^ ((q >> 1) & 3);
                bx[j].u = *(const u32x4*)(xsb + ((prow[j] + dy) * 64 + q) * 32 + slot * 8);
            }
            __builtin_amdgcn_s_setprio(1);            // favor MFMA-burst waves (T5)
            #pragma unroll
            for (int j = 0; j < 7; ++j) {
                acc[0][j] = __builtin_amdgcn_mfma_f32_16x16x32_bf16(bx[j].b, wf[0].b, acc[0][j], 0, 0, 0);
                acc[1][j] = __builtin_amdgcn_mfma_f32_16x16x32_bf16(bx[j].b, wf[1].b, acc[1][j], 0, 0, 0);
                acc[2][j] = __builtin_amdgcn_mfma_f32_16x16x32_bf16(bx[j].b, wf[2].b, acc[2][j], 0, 0, 0);
                acc[3][j] = __builtin_amdgcn_mfma_f32_16x16x32_bf16(bx[j].b, wf[3].b, acc[3][j], 0, 0, 0);
            }
            __builtin_amdgcn_s_setprio(0);
        };
        auto reload = [&](U16B (&wf)[4], int tap) {
            const ush* wnx = wc + (size_t)tap * 65536;
            #pragma unroll
            for (int mi = 0; mi < 4; ++mi) wf[mi].u = *(const u32x4*)(wnx + mi * 4096);
        };

        do_tap(0, 0, wA[0]);                        // tap 0
        do_tap(0, 1, wA[1]);                        // tap 1
        reload(wA[0], 4); reload(wA[1], 5);
        do_tap(0, 2, wB[0]);                        // tap 2
        do_tap(1, 0, wB[1]);                        // tap 3
        reload(wB[0], 6); reload(wB[1], 7);
        do_tap(1, 1, wA[0]);                        // tap 4
        do_tap(1, 2, wA[1]);                        // tap 5
        reload(wA[0], 8);
        do_tap(2, 0, wB[0]);                        // tap 6
        do_tap(2, 1, wB[1]);                        // tap 7
        do_tap(2, 2, wA[0]);                        // tap 8

        __syncthreads();   // drains chunk-old DMAs (cheap) + orders buffer swap
    };

    for (int i2 = 0; i2 < 8; i2 += 2) {
        chunk_body(ICx<0>{}, i2);
        chunk_body(ICx<1>{}, i2 + 1);
    }

    // epilogue: D row = px (4 consecutive per lane via s4), col = oc (l15)
    int pxbase = row0 * 56 + wn * 112 + s4 * 4;
    #pragma unroll
    for (int mi = 0; mi < 4; ++mi) {
        int oc = oc0 + wm * 64 + mi * 16 + l15;
        float* o = out + (size_t)(b * 256 + oc) * HWPX + pxbase;
        #pragma unroll
        for (int j = 0; j < 7; ++j)
            *(f32x4*)(o + j * 16) = acc[mi][j];
    }
}

// ---------------- launcher ----------------
extern "C" void kernel_launch(void* const* d_in, const int* in_sizes, int n_in,
                              void* d_out, int out_size, void* d_ws, size_t ws_size,
                              hipStream_t stream) {
    const float* x     = (const float*)d_in[0];
    const float* cells = (const float*)d_in[1];
    const float* fc1_w = (const float*)d_in[2];
    const float* fc1_b = (const float*)d_in[3];
    const float* ln_g  = (const float*)d_in[4];
    const float* ln_b  = (const float*)d_in[5];
    const float* sp_w  = (const float*)d_in[6];
    const float* sp_b  = (const float*)d_in[7];
    float* out = (float*)d_out;

    char* ws = (char*)d_ws;
    ush*   xT     = (ush*)ws;
    float* pooled = (float*)(ws + POOL_OFF);
    float* att    = (float*)(ws + ATT_OFF);
    ush*   wagg   = (ush*)(ws + WAGG_OFF);

    k_halo<<<448, 256, 0, stream>>>((u32x4*)ws, (u32x4*)pooled);
    k_transpose<<<6272, 256, 0, stream>>>(x, xT, pooled);
    k_attn<<<1, 512, 0, stream>>>(pooled, fc1_w, fc1_b, ln_g, ln_b, sp_w, sp_b, att);
    k_agg<<<2048, 256, 0, stream>>>(cells, att, wagg);
    k_conv<<<896, 256, 0, stream>>>(xT, wagg, out);
}

// Round 9
// 234.409 us; speedup vs baseline: 4.3047x; 4.3047x over previous
//
#include <hip/hip_runtime.h>
#include <stdint.h>

// ---------------- types ----------------
typedef unsigned short ush;
typedef __bf16   bf16x8 __attribute__((ext_vector_type(8)));
typedef float    f32x4  __attribute__((ext_vector_type(4)));
typedef uint32_t u32x4  __attribute__((ext_vector_type(4)));

union U16B { u32x4 u; bf16x8 b; };
union P8   { ush us[8]; u32x4 v; };

__device__ __forceinline__ ush f2bf(float f) {
    union { float f; uint32_t u; } v; v.f = f;
    uint32_t r = v.u + 0x7FFFu + ((v.u >> 16) & 1u);   // RNE
    return (ush)(r >> 16);
}

__device__ __forceinline__ void gl_lds16(const ush* g, ush* l) {
    __builtin_amdgcn_global_load_lds(
        (const __attribute__((address_space(1))) uint32_t*)g,
        (__attribute__((address_space(3))) uint32_t*)l, 16, 0, 0);
}

// problem constants
#define HWPX  3136
// ws layout (bytes)
#define POOL_OFF   58720256UL   // 8192 f32
#define ATT_OFF    58753024UL   // 16384 f32
#define WAGG_OFF   58818560UL   // 32*9*256*256 bf16

// ---------------- kernel 0: zero xT halo cols {0,57} + pooled ----------------
__global__ void k_halo(u32x4* __restrict__ xT16, u32x4* __restrict__ pooled16) {
    int i = blockIdx.x * 256 + threadIdx.x;        // 448 blocks -> 114688
    int rl = i >> 3, s = i & 7;
    u32x4 z = (u32x4)(0u);
    size_t byte = (size_t)rl * 4096 + (s < 4 ? s * 16 : 3648 + (s - 4) * 16);
    xT16[byte >> 4] = z;
    if (blockIdx.x < 8) pooled16[blockIdx.x * 256 + threadIdx.x] = z;  // full 32KB
}

// ---------------- kernel 1: transpose x -> xT bf16 (swizzled) + pooled sums --
// xT layout: [b][icg32 0..7][row 0..55][padcol 0..63][ic 0..31]
//   padcol p: p=0 and p=57 are zero halo; p=1..56 <-> image col p-1; 58..63 dead
//   sub 's' stored at slot s ^ ((p>>1)&3): injective on every 8-col window
__global__ void k_transpose(const float* __restrict__ x, ush* __restrict__ xT,
                            float* __restrict__ pooled) {
    __shared__ float tile[64][65];
    int blk = blockIdx.x;                 // 32 * 4 * 49
    int b   = blk / 196;
    int rem = blk % 196;
    int icg = rem / 49;                   // 64-ic group
    int pxg = rem % 49;                   // 64-px group
    int t = threadIdx.x;

    {
        int icl  = t >> 2, part = t & 3;
        const float* src = x + (size_t)(b * 256 + icg * 64 + icl) * HWPX + pxg * 64 + part * 16;
        #pragma unroll
        for (int k = 0; k < 4; ++k) {
            f32x4 v = *(const f32x4*)(src + k * 4);
            tile[icl][part * 16 + k * 4 + 0] = v[0];
            tile[icl][part * 16 + k * 4 + 1] = v[1];
            tile[icl][part * 16 + k * 4 + 2] = v[2];
            tile[icl][part * 16 + k * 4 + 3] = v[3];
        }
    }
    __syncthreads();

    if (t < 64) {
        float s = 0.f;
        #pragma unroll 8
        for (int p = 0; p < 64; ++p) s += tile[t][p];
        atomicAdd(pooled + b * 256 + icg * 64 + t, s);
    }

    {
        int pxl = t >> 2, icq = t & 3;
        int px  = pxg * 64 + pxl;
        int row = px / 56;
        int col = px - row * 56;
        int p   = col + 1;
        int xorp = (p >> 1) & 3;
        int icg32   = icg * 2 + (icq >> 1);
        int subbase = (icq & 1) * 2;
        P8 lo, hi;
        #pragma unroll
        for (int m = 0; m < 8; ++m) {
            lo.us[m] = f2bf(tile[icq * 16 + m][pxl]);
            hi.us[m] = f2bf(tile[icq * 16 + 8 + m][pxl]);
        }
        size_t base = (((size_t)(b * 8 + icg32) * 56 + row) * 64 + p) * 32;
        *(u32x4*)(xT + base + (size_t)((subbase ^ xorp) * 8))       = lo.v;
        *(u32x4*)(xT + base + (size_t)(((subbase + 1) ^ xorp) * 8)) = hi.v;
    }
}

// ---------------- kernel 2: attention (1 block, 512 threads) ----------------
__global__ void k_attn(const float* __restrict__ pooled,
                       const float* __restrict__ fc1_w, const float* __restrict__ fc1_b,
                       const float* __restrict__ ln_g,  const float* __restrict__ ln_b,
                       const float* __restrict__ sp_w,  const float* __restrict__ sp_b,
                       float* __restrict__ att) {
    __shared__ float hs[32][16];
    int t = threadIdx.x;
    {
        int b = t >> 4, j = t & 15;
        float acc = 0.f;
        for (int c = 0; c < 256; ++c) acc += pooled[b * 256 + c] * fc1_w[j * 256 + c];
        hs[b][j] = fc1_b[j] + acc * (1.0f / 3136.0f);
    }
    __syncthreads();
    if (t < 32) {
        float mu = 0.f;
        #pragma unroll
        for (int j = 0; j < 16; ++j) mu += hs[t][j];
        mu *= (1.0f / 16.0f);
        float var = 0.f;
        #pragma unroll
        for (int j = 0; j < 16; ++j) { float d = hs[t][j] - mu; var += d * d; }
        var *= (1.0f / 16.0f);
        float inv = rsqrtf(var + 1e-5f);
        #pragma unroll
        for (int j = 0; j < 16; ++j) {
            float v = (hs[t][j] - mu) * inv * ln_g[j] + ln_b[j];
            hs[t][j] = fmaxf(v, 0.f);
        }
    }
    __syncthreads();
    {
        int b = t >> 4, m = t & 15;
        float a[33];
        #pragma unroll 1
        for (int i = 0; i < 33; ++i) {
            int p = m * 33 + i;
            float acc = sp_b[p];
            #pragma unroll
            for (int j = 0; j < 16; ++j) acc += hs[b][j] * sp_w[p * 16 + j];
            a[i] = acc;
        }
        float s = 0.f;
        #pragma unroll
        for (int i = 0; i < 33; ++i) s += fabsf(a[i]);
        float inv = 1.0f / (s + 0.001f);
        #pragma unroll
        for (int c = 0; c < 32; ++c) att[(b * 16 + m) * 32 + c] = a[c] * inv;
    }
}

// ---------------- kernel 3: aggregate weights -> Wagg bf16 [b][tap][oc][ic] --
__global__ void k_agg(const float* __restrict__ cells, const float* __restrict__ att,
                      ush* __restrict__ wagg) {
    __shared__ float at[512];
    int blk = blockIdx.x;                 // 32*64
    int b = blk >> 6, co = blk & 63;
    int t = threadIdx.x;
    for (int i = t; i < 512; i += 256) at[i] = att[b * 512 + i];
    __syncthreads();
    int ci = t & 63, gi = t >> 6;
    float acc[4][9];
    #pragma unroll
    for (int g = 0; g < 4; ++g)
        #pragma unroll
        for (int k = 0; k < 9; ++k) acc[g][k] = 0.f;
    for (int c = 0; c < 32; ++c) {
        float a0 = at[(0 + gi) * 32 + c];
        float a1 = at[(4 + gi) * 32 + c];
        float a2 = at[(8 + gi) * 32 + c];
        float a3 = at[(12 + gi) * 32 + c];
        const float* cp = cells + (size_t)c * 36864 + co * 576 + ci * 9;
        #pragma unroll
        for (int k = 0; k < 9; ++k) {
            float cv = cp[k];
            acc[0][k] += a0 * cv; acc[1][k] += a1 * cv;
            acc[2][k] += a2 * cv; acc[3][k] += a3 * cv;
        }
    }
    #pragma unroll
    for (int g = 0; g < 4; ++g)
        #pragma unroll
        for (int k = 0; k < 9; ++k)
            wagg[((size_t)(b * 9 + k) * 256 + g * 64 + co) * 256 + gi * 64 + ci] = f2bf(acc[g][k]);
}

// ---------------- kernel 4: conv via implicit-GEMM MFMA, weights in LDS -----
// block = 224 px (4 rows) x 64 oc; 4 waves = 2 px-halves x 2 oc-halves (112x32)
// LDS: x single-buffer [6 rows][64 cols][32 ic] (24,576 B)
//      w per-chunk    [9 taps][64 oc, 80 B stride][4 slots x 16 B] (46,080 B)
// Per chunk: stage (w global->reg->ds_write + x gl_lds) / barrier / 9 taps of
// {2 wf + 7 bx LDS reads -> 14 MFMA} / barrier. Weight L2 latency is paid once
// per chunk behind the barrier instead of per-tap per-wave (R7: V2 proved the
// LDS-fed skeleton runs ~2x faster than the global-weight-stream version).
__global__ __launch_bounds__(256, 2) void k_conv(const ush* __restrict__ xT,
                                                 const ush* __restrict__ wagg,
                                                 float* __restrict__ out) {
    __shared__ __align__(16) ush xs[12288];      // 24,576 B
    __shared__ __align__(16) ush wsh[23040];     // 46,080 B

    int tid = threadIdx.x;
    int wg  = blockIdx.x;                // 1792
    int xcd = wg & 7;
    int kk  = wg >> 3;                   // 0..223
    int gq  = kk / 14;                   // 0..15
    int sp  = kk - gq * 14;              // spatial tile 0..13
    int g   = gq * 8 + xcd;              // 0..127
    int b   = g >> 2, octile = g & 3;
    int row0 = sp * 4, oc0 = octile * 64;

    int lane = tid & 63, w = tid >> 6;
    int wm = w >> 1, wn = w & 1;         // wm: oc half (32), wn: px half (112)
    int l15 = lane & 15, s4 = lane >> 4;

    {   // zero x LDS once (invalid halo rows stay zero forever)
        u32x4 z = (u32x4)(0u);
        #pragma unroll
        for (int i = 0; i < 6; ++i) ((u32x4*)xs)[tid + i * 256] = z;
    }

    int prow[7], pq[7];
    #pragma unroll
    for (int j = 0; j < 7; ++j) {
        int px = wn * 112 + j * 16 + l15;
        prow[j] = px / 56;
        pq[j]   = px - prow[j] * 56;
    }

    unsigned vmask = 0;
    #pragma unroll
    for (int k = 0; k < 6; ++k) {
        int grow = row0 - 1 + k;
        if (grow >= 0 && grow < 56) vmask |= 1u << k;
    }

    // weight staging: thread -> (oc_l = tid>>2, s = tid&3), one 16B item per tap
    const ush* wgl = wagg + (size_t)b * 9 * 65536 + (size_t)(oc0 + (tid >> 2)) * 256 + (tid & 3) * 8;
    ush* wdst = wsh + (tid >> 2) * 40 + (((tid & 3) ^ ((tid >> 2) & 3)) * 8);
    // weight frag read base: oc_local = wm*32 + mi*16 + l15, slot = s4 ^ (l15&3)
    const ush* wrd = wsh + (wm * 32 + l15) * 40 + ((s4 ^ (l15 & 3)) * 8);
    // x DMA source (per-lane 16B within a row line)
    const ush* xb = xT + (size_t)b * 8 * 56 * 2048 + (size_t)tid * 8;

    f32x4 acc[2][7];
    #pragma unroll
    for (int mi = 0; mi < 2; ++mi)
        #pragma unroll
        for (int j = 0; j < 7; ++j) acc[mi][j] = (f32x4)(0.f);

    __syncthreads();                      // x-zero visible

    // half-phase skew: de-phase the co-resident block pair on each CU so one
    // block's stage phase overlaps the other's compute phase
    if ((kk >> 5) & 1) __builtin_amdgcn_s_sleep(32);

    for (int cc = 0; cc < 8; ++cc) {
        // ---- stage phase ----
        U16B wst[9];
        const ush* wcg = wgl + (size_t)cc * 32;
        #pragma unroll
        for (int k = 0; k < 9; ++k) wst[k].u = *(const u32x4*)(wcg + (size_t)k * 65536);
        #pragma unroll
        for (int k = 0; k < 6; ++k)
            if (vmask & (1u << k))
                gl_lds16(xb + (size_t)(cc * 56 + row0 - 1 + k) * 2048, xs + k * 2048 + w * 512);
        #pragma unroll
        for (int k = 0; k < 9; ++k) *(u32x4*)(wdst + k * 2560) = wst[k].u;
        __syncthreads();                  // drains DMA + ds_writes

        // ---- compute phase: 9 taps ----
        #pragma unroll
        for (int tap = 0; tap < 9; ++tap) {
            const int dy = tap / 3, dx = tap % 3;
            U16B wf0, wf1;
            wf0.u = *(const u32x4*)(wrd + tap * 2560);
            wf1.u = *(const u32x4*)(wrd + tap * 2560 + 16 * 40);
            U16B bx[7];
            #pragma unroll
            for (int j = 0; j < 7; ++j) {
                int q    = pq[j] + dx;
                int slot = s4 ^ ((q >> 1) & 3);
                bx[j].u = *(const u32x4*)(xs + ((prow[j] + dy) * 64 + q) * 32 + slot * 8);
            }
            __builtin_amdgcn_s_setprio(1);
            #pragma unroll
            for (int j = 0; j < 7; ++j) {
                acc[0][j] = __builtin_amdgcn_mfma_f32_16x16x32_bf16(bx[j].b, wf0.b, acc[0][j], 0, 0, 0);
                acc[1][j] = __builtin_amdgcn_mfma_f32_16x16x32_bf16(bx[j].b, wf1.b, acc[1][j], 0, 0, 0);
            }
            __builtin_amdgcn_s_setprio(0);
        }
        __syncthreads();                  // protect LDS before next stage
    }

    // epilogue: D row = px (4 consecutive per lane via s4), col = oc (l15)
    int pxbase = row0 * 56 + wn * 112 + s4 * 4;
    #pragma unroll
    for (int mi = 0; mi < 2; ++mi) {
        int oc = oc0 + wm * 32 + mi * 16 + l15;
        float* o = out + (size_t)(b * 256 + oc) * HWPX + pxbase;
        #pragma unroll
        for (int j = 0; j < 7; ++j)
            *(f32x4*)(o + j * 16) = acc[mi][j];
    }
}

// ---------------- launcher ----------------
extern "C" void kernel_launch(void* const* d_in, const int* in_sizes, int n_in,
                              void* d_out, int out_size, void* d_ws, size_t ws_size,
                              hipStream_t stream) {
    const float* x     = (const float*)d_in[0];
    const float* cells = (const float*)d_in[1];
    const float* fc1_w = (const float*)d_in[2];
    const float* fc1_b = (const float*)d_in[3];
    const float* ln_g  = (const float*)d_in[4];
    const float* ln_b  = (const float*)d_in[5];
    const float* sp_w  = (const float*)d_in[6];
    const float* sp_b  = (const float*)d_in[7];
    float* out = (float*)d_out;

    char* ws = (char*)d_ws;
    ush*   xT     = (ush*)ws;
    float* pooled = (float*)(ws + POOL_OFF);
    float* att    = (float*)(ws + ATT_OFF);
    ush*   wagg   = (ush*)(ws + WAGG_OFF);

    k_halo<<<448, 256, 0, stream>>>((u32x4*)ws, (u32x4*)pooled);
    k_transpose<<<6272, 256, 0, stream>>>(x, xT, pooled);
    k_attn<<<1, 512, 0, stream>>>(pooled, fc1_w, fc1_b, ln_g, ln_b, sp_w, sp_b, att);
    k_agg<<<2048, 256, 0, stream>>>(cells, att, wagg);
    k_conv<<<1792, 256, 0, stream>>>(xT, wagg, out);
}